// Round 8
// baseline (243.114 us; speedup 1.0000x reference)
//
#include <hip/hip_runtime.h>

#define BB 128
#define NN 8192
#define SS 100
#define KK 512
#define NT 256                 // 4 waves per block; waves fully independent
#define WPB 4
#define NROWS (BB * SS)        // 12800 rows, one per wave
#define NCH 32                 // 256-element chunks per row
#define CAND 256
#define NBIN 256

__device__ __forceinline__ float fast_ln(float x) {
    return __builtin_amdgcn_logf(x) * 0.69314718056f;   // v_log_f32 * ln2
}
// Deterministic: bit-identical p everywhere it's computed.
__device__ __forceinline__ float p_of(float u, float lgv) {
    return lgv - fast_ln(-fast_ln(u + 1e-20f) + 1e-20f);
}
// Monotone map [2,23] -> 1..255 (u8); p<2 -> 0 (catch-all, count implied).
// K-th of 8192 sits at p~3.3; count(p>=2)~1550 >> 512, so bin 0 is never
// selected on this data; exact bisection cold path covers it anyway.
__device__ __forceinline__ int binHot(float p) {
    const float SC = 255.0f / 21.0f;
    const float OF = 1.0f - 2.0f * SC;
    int b = (int)fmaf(p, SC, OF);
    b = b < 0 ? 0 : b;
    return b > 255 ? 255 : b;
}

// One WAVE handles one (b,s) row; no __syncthreads anywhere.
// MODE 0: write membership bitmap (256 dwords/row) to ws. MODE 1: atomicAdd out.
template <int MODE>
__global__ __launch_bounds__(NT) void gumbel_topk_kernel(
    const float* __restrict__ logits,
    const float* __restrict__ uniform,
    unsigned* __restrict__ ws,
    float* __restrict__ out) {

    __shared__ int      shist[WPB][NBIN];
    __shared__ float    sck[WPB][CAND];
    __shared__ int      sci[WPB][CAND];
    __shared__ unsigned smem[WPB][256];
    __shared__ int      scnt[WPB];

    const int tid  = threadIdx.x;
    const int lane = tid & 63;
    const int wv   = tid >> 6;
    const int row  = blockIdx.x * WPB + wv;      // 0..12799
    const int b    = row / SS;
    const float* lrow = logits + (size_t)b * NN;
    const float* urow = uniform + (size_t)row * NN;   // [B,S,n] row-major

    int*      hb   = shist[wv];
    float*    ck   = sck[wv];
    int*      ci   = sci[wv];
    unsigned* mrow = smem[wv];

    // wave-private init (ordering vs later DS ops is wave-internal lgkmcnt)
    *reinterpret_cast<int4*>(&hb[lane * 4]) = make_int4(0, 0, 0, 0);
    if (lane == 0) scnt[wv] = 0;

    // ---- pass A: stream u+logits, bin, wave-private histogram (p>=2 only)
    unsigned bpack[NCH];                 // 4 x u8 bins per dword, static idx
#pragma unroll
    for (int c = 0; c < NCH; ++c) {
        const float4 uv = *reinterpret_cast<const float4*>(&urow[c * 256 + lane * 4]);
        const float4 lv = *reinterpret_cast<const float4*>(&lrow[c * 256 + lane * 4]);
        const int b0 = binHot(p_of(uv.x, lv.x));
        const int b1 = binHot(p_of(uv.y, lv.y));
        const int b2 = binHot(p_of(uv.z, lv.z));
        const int b3 = binHot(p_of(uv.w, lv.w));
        if (b0) atomicAdd(&hb[b0], 1);
        if (b1) atomicAdd(&hb[b1], 1);
        if (b2) atomicAdd(&hb[b2], 1);
        if (b3) atomicAdd(&hb[b3], 1);
        bpack[c] = (unsigned)b0 | ((unsigned)b1 << 8) |
                   ((unsigned)b2 << 16) | ((unsigned)b3 << 24);
    }
    asm volatile("s_waitcnt lgkmcnt(0)" ::: "memory");

    // ---- wave-local scan: suffix-sum 256 bins, locate K-th bin (no barrier)
    const int4 h = *reinterpret_cast<const int4*>(&hb[lane * 4]);
    const int s4 = h.x + h.y + h.z + h.w;
    int suf = s4;
#pragma unroll
    for (int d = 1; d < 64; d <<= 1) {
        const int o = __shfl_down(suf, d);
        if (lane + d < 64) suf += o;
    }
    int selBin = -1, kkf = 0;
    int cum = suf - s4;                       // count in strictly higher bins
    if (cum < KK && cum + h.w >= KK) { selBin = lane * 4 + 3; kkf = KK - cum; }
    cum += h.w;
    if (selBin < 0 && cum < KK && cum + h.z >= KK) { selBin = lane * 4 + 2; kkf = KK - cum; }
    cum += h.z;
    if (selBin < 0 && cum < KK && cum + h.y >= KK) { selBin = lane * 4 + 1; kkf = KK - cum; }
    cum += h.y;
    if (selBin < 0 && cum < KK && cum + h.x >= KK) { selBin = lane * 4 + 0; kkf = KK - cum; }

    const unsigned long long mk = __ballot(selBin > 0);   // bin 0 => cold path

    if (mk) {
        // ---- hot path
        const int src    = __builtin_ctzll(mk);
        const int packed = __shfl(selBin | (kkf << 8), src);
        const int sel    = packed & 255;
        const int kkv    = packed >> 8;

        // base membership bits (bin > sel) + push threshold-bin candidates
        unsigned mb0 = 0, mb1 = 0, mb2 = 0, mb3 = 0;
#pragma unroll
        for (int c = 0; c < NCH; ++c) {
            const unsigned w = bpack[c];
            const int q0 = (w >> 0)  & 255, q1 = (w >> 8)  & 255;
            const int q2 = (w >> 16) & 255, q3 = (w >> 24) & 255;
            if (q0 > sel) mb0 |= 1u << c;
            if (q1 > sel) mb1 |= 1u << c;
            if (q2 > sel) mb2 |= 1u << c;
            if (q3 > sel) mb3 |= 1u << c;
            if (q0 == sel) { const int p0 = atomicAdd(&scnt[wv], 1); if (p0 < CAND) ci[p0] = c * 256 + lane * 4 + 0; }
            if (q1 == sel) { const int p1 = atomicAdd(&scnt[wv], 1); if (p1 < CAND) ci[p1] = c * 256 + lane * 4 + 1; }
            if (q2 == sel) { const int p2 = atomicAdd(&scnt[wv], 1); if (p2 < CAND) ci[p2] = c * 256 + lane * 4 + 2; }
            if (q3 == sel) { const int p3 = atomicAdd(&scnt[wv], 1); if (p3 < CAND) ci[p3] = c * 256 + lane * 4 + 3; }
        }
        mrow[0 * 64 + lane] = mb0;
        mrow[1 * 64 + lane] = mb1;
        mrow[2 * 64 + lane] = mb2;
        mrow[3 * 64 + lane] = mb3;
        asm volatile("s_waitcnt lgkmcnt(0)" ::: "memory");

        const int c2 = scnt[wv] < CAND ? scnt[wv] : CAND;
        // fill candidate keys (exact recompute, L2-hot scattered loads)
        for (int m = lane; m < c2; m += 64) {
            const int gi = ci[m];
            ck[m] = p_of(urow[gi], lrow[gi]);
        }
        asm volatile("s_waitcnt lgkmcnt(0) vmcnt(0)" ::: "memory");

        // rank each candidate (key desc, index asc = JAX tie-break), scatter
        for (int m = lane; m < c2; m += 64) {
            const float kv = ck[m];
            const int   gi = ci[m];
            int rank = 0;
            for (int t2 = 0; t2 < c2; ++t2) {
                const float ko = ck[t2];
                rank += (ko > kv || (ko == kv && ci[t2] < gi)) ? 1 : 0;
            }
            if (rank < kkv)
                atomicOr(&mrow[((gi & 3) << 6) | ((gi >> 2) & 63)], 1u << (gi >> 8));
        }
    } else {
        // ---- cold path (never taken on this data; exact): bisection on T
        float loT = -12.0f, hiT = 2.0f;     // gumbel >= -3.84, |logit| < 7
        for (int it = 0; it < 64; ++it) {
            const float mid = 0.5f * (loT + hiT);
            int cl = 0;
            for (int c = 0; c < NCH; ++c) {
                const float4 uv = *reinterpret_cast<const float4*>(&urow[c * 256 + lane * 4]);
                const float4 lv = *reinterpret_cast<const float4*>(&lrow[c * 256 + lane * 4]);
                cl += (p_of(uv.x, lv.x) > mid) + (p_of(uv.y, lv.y) > mid)
                    + (p_of(uv.z, lv.z) > mid) + (p_of(uv.w, lv.w) > mid);
            }
#pragma unroll
            for (int d = 32; d; d >>= 1) cl += __shfl_down(cl, d);
            const int ctot = __shfl(cl, 0);
            if (ctot >= KK) loT = mid; else hiT = mid;
        }
        unsigned mb0 = 0, mb1 = 0, mb2 = 0, mb3 = 0;
        int na = 0;
        for (int c = 0; c < NCH; ++c) {
            const float4 uv = *reinterpret_cast<const float4*>(&urow[c * 256 + lane * 4]);
            const float4 lv = *reinterpret_cast<const float4*>(&lrow[c * 256 + lane * 4]);
            const float p0 = p_of(uv.x, lv.x), p1 = p_of(uv.y, lv.y);
            const float p2 = p_of(uv.z, lv.z), p3 = p_of(uv.w, lv.w);
            if (p0 > hiT) { mb0 |= 1u << c; ++na; }
            else if (p0 > loT) { const int q = atomicAdd(&scnt[wv], 1); if (q < CAND) { ck[q] = p0; ci[q] = c * 256 + lane * 4 + 0; } }
            if (p1 > hiT) { mb1 |= 1u << c; ++na; }
            else if (p1 > loT) { const int q = atomicAdd(&scnt[wv], 1); if (q < CAND) { ck[q] = p1; ci[q] = c * 256 + lane * 4 + 1; } }
            if (p2 > hiT) { mb2 |= 1u << c; ++na; }
            else if (p2 > loT) { const int q = atomicAdd(&scnt[wv], 1); if (q < CAND) { ck[q] = p2; ci[q] = c * 256 + lane * 4 + 2; } }
            if (p3 > hiT) { mb3 |= 1u << c; ++na; }
            else if (p3 > loT) { const int q = atomicAdd(&scnt[wv], 1); if (q < CAND) { ck[q] = p3; ci[q] = c * 256 + lane * 4 + 3; } }
        }
        mrow[0 * 64 + lane] = mb0;
        mrow[1 * 64 + lane] = mb1;
        mrow[2 * 64 + lane] = mb2;
        mrow[3 * 64 + lane] = mb3;
#pragma unroll
        for (int d = 32; d; d >>= 1) na += __shfl_down(na, d);
        const int kkc = KK - __shfl(na, 0);
        asm volatile("s_waitcnt lgkmcnt(0)" ::: "memory");
        const int c2 = scnt[wv] < CAND ? scnt[wv] : CAND;
        for (int m = lane; m < c2; m += 64) {
            const float kv = ck[m];
            const int   gi = ci[m];
            int rank = 0;
            for (int t2 = 0; t2 < c2; ++t2) {
                const float ko = ck[t2];
                rank += (ko > kv || (ko == kv && ci[t2] < gi)) ? 1 : 0;
            }
            if (rank < kkc)
                atomicOr(&mrow[((gi & 3) << 6) | ((gi >> 2) & 63)], 1u << (gi >> 8));
        }
    }
    asm volatile("s_waitcnt lgkmcnt(0)" ::: "memory");

    // ---- emit: bitmap row (coalesced) or atomic fallback
    if (MODE == 0) {
        unsigned* wr = ws + (size_t)row * 256;
#pragma unroll
        for (int j = 0; j < 4; ++j) wr[j * 64 + lane] = mrow[j * 64 + lane];
    } else {
        float* orow = out + (size_t)b * NN;
#pragma unroll
        for (int j = 0; j < 4; ++j) {
            unsigned w = mrow[j * 64 + lane];
            while (w) {
                const int c = __ffs(w) - 1; w &= w - 1;
                atomicAdd(&orow[c * 256 + lane * 4 + j], 0.01f);
            }
        }
    }
}

// Popcount-reduce: out[b][c*256 + l*4 + j] = 0.01 * sum_s bit_c(ws[b,s][j*64+l]).
// Block = (b, qq): c in [qq*8, qq*8+8). Thread t -> (l = t>>2, j = t&3).
__global__ __launch_bounds__(256) void reduce_kernel(
    const unsigned* __restrict__ ws, float* __restrict__ out) {
    const int blk = blockIdx.x;
    const int b   = blk >> 2;
    const int qq  = blk & 3;
    const int t   = threadIdx.x;
    const int l   = t >> 2;
    const int j   = t & 3;
    const unsigned* base = ws + (size_t)b * SS * 256 + (j * 64 + l);
    int cnt[8] = {0, 0, 0, 0, 0, 0, 0, 0};
    for (int s = 0; s < SS; ++s) {
        const unsigned w = base[s * 256] >> (qq * 8);
#pragma unroll
        for (int cc = 0; cc < 8; ++cc) cnt[cc] += (w >> cc) & 1;
    }
    float* ob = out + (size_t)b * NN + (qq * 8) * 256 + t;
#pragma unroll
    for (int cc = 0; cc < 8; ++cc) ob[cc * 256] = (float)cnt[cc] * 0.01f;
}

extern "C" void kernel_launch(void* const* d_in, const int* in_sizes, int n_in,
                              void* d_out, int out_size, void* d_ws, size_t ws_size,
                              hipStream_t stream) {
    const float* logits  = (const float*)d_in[0];   // [128, 8192] f32
    const float* uniform = (const float*)d_in[1];   // [128, 100, 8192] f32
    float* out = (float*)d_out;                     // [128, 8192] f32

    const size_t need = (size_t)NROWS * 256 * sizeof(unsigned);   // 13.1 MB

    if (ws_size >= need) {
        gumbel_topk_kernel<0><<<NROWS / WPB, NT, 0, stream>>>(
            logits, uniform, (unsigned*)d_ws, nullptr);
        reduce_kernel<<<BB * 4, 256, 0, stream>>>((const unsigned*)d_ws, out);
    } else {
        hipMemsetAsync(out, 0, (size_t)out_size * sizeof(float), stream);
        gumbel_topk_kernel<1><<<NROWS / WPB, NT, 0, stream>>>(
            logits, uniform, nullptr, out);
    }
}

// Round 9
// 123.874 us; speedup vs baseline: 1.9626x; 1.9626x over previous
//
#include <hip/hip_runtime.h>

#define BB 128
#define NN 8192
#define SS 100
#define KK 512
#define SPLIT 50               // sample PAIRS per batch row (SPB=2)
#define NT 1024                // 16 waves
#define EPT 8                  // elements per thread per sample
#define CAND 512
#define NBIN 2048
#define NWAVE 16

#define GIDX(e) (((e) >> 2) * 4096 + tid * 4 + ((e) & 3))

// LDS-only barrier: waits DS ops (lgkmcnt) but leaves global loads in
// flight (unlike __syncthreads, which drains vmcnt(0) too). All cross-wave
// communication in this kernel is via LDS. sched_barrier stops the
// compiler hoisting LDS reads above the wait (guide rule #18).
__device__ __forceinline__ void lds_barrier() {
    asm volatile("s_waitcnt lgkmcnt(0)" ::: "memory");
    __builtin_amdgcn_s_barrier();
    __builtin_amdgcn_sched_barrier(0);
}

// Monotone linear bin map [-12,24] -> [0,2047]. Range never clamps for this
// op (p in [-8.4, 21.3]); clamped bins would still be exact via in-bin rank.
__device__ __forceinline__ int bin_of(float p) {
    const float SC = 2048.0f / 36.0f;
    const float OF = 12.0f * SC;
    int b = (int)fmaf(p, SC, OF);
    b = b < 0 ? 0 : b;
    return b > 2047 ? 2047 : b;
}
__device__ __forceinline__ float fast_ln(float x) {
    return __builtin_amdgcn_logf(x) * 0.69314718056f;   // v_log_f32 * ln2
}
__device__ __forceinline__ float p_of(float u, float lgv) {
    return lgv - fast_ln(-fast_ln(u + 1e-20f) + 1e-20f);
}

// One block = (b, pair of samples). 5 LDS-barriers per block, all global
// loads issued upfront and never drained by a barrier.
// MODE 0: write 2-bit-packed counts (u16/thread) to ws. MODE 1: atomicAdd out.
template <int MODE>
__global__ __launch_bounds__(NT, 8) void gumbel_topk_kernel(
    const float* __restrict__ logits,
    const float* __restrict__ uniform,
    unsigned short* __restrict__ ws,
    float* __restrict__ out) {

    __shared__ __align__(16) int histA[NBIN];
    __shared__ __align__(16) int histB[NBIN];
    __shared__ float ckA[CAND];
    __shared__ int   ciA[CAND];
    __shared__ float ckB[CAND];
    __shared__ int   ciB[CAND];
    __shared__ int waveTotA[NWAVE], waveTotB[NWAVE];
    __shared__ int bselA, bkkA, bselB, bkkB, cntA, cntB;

    const int tid  = threadIdx.x;
    const int lane = tid & 63;
    const int wv   = tid >> 6;
    const int b    = blockIdx.x / SPLIT;
    const int ch   = blockIdx.x % SPLIT;

    const float* lrow  = logits + (size_t)b * NN;
    const float* uArow = uniform + ((size_t)b * SS + ch * 2) * NN;
    const float* uBrow = uArow + NN;

    // ---- issue ALL global loads upfront; they stay in flight across s0
    float lg[EPT], pA[EPT], pB[EPT];
#pragma unroll
    for (int j = 0; j < 2; ++j) {
        *reinterpret_cast<float4*>(&pA[j * 4]) =
            *reinterpret_cast<const float4*>(&uArow[j * 4096 + tid * 4]);
        *reinterpret_cast<float4*>(&pB[j * 4]) =
            *reinterpret_cast<const float4*>(&uBrow[j * 4096 + tid * 4]);
        *reinterpret_cast<float4*>(&lg[j * 4]) =
            *reinterpret_cast<const float4*>(&lrow[j * 4096 + tid * 4]);
    }

    // ---- init LDS
    *reinterpret_cast<int2*>(&histA[tid * 2]) = make_int2(0, 0);
    *reinterpret_cast<int2*>(&histB[tid * 2]) = make_int2(0, 0);
    if (tid == 0) { cntA = 0; cntB = 0; }
    lds_barrier();                                        // s0

    // ---- transform + histogram both samples (vmcnt waits happen here, at use)
#pragma unroll
    for (int e = 0; e < EPT; ++e) {
        pA[e] = p_of(pA[e], lg[e]);
        pB[e] = p_of(pB[e], lg[e]);
        atomicAdd(&histA[bin_of(pA[e])], 1);
        atomicAdd(&histB[bin_of(pB[e])], 1);
    }
    lds_barrier();                                        // s1

    // ---- wave suffix scans over both hists (2 bins/thread)
    const int base = tid * 2;
    const int2 hA = *reinterpret_cast<const int2*>(&histA[base]);
    const int2 hB = *reinterpret_cast<const int2*>(&histB[base]);
    const int sumA = hA.x + hA.y, sumB = hB.x + hB.y;
    int sufA = sumA, sufB = sumB;
#pragma unroll
    for (int d = 1; d < 64; d <<= 1) {
        const int oA = __shfl_down(sufA, d);
        const int oB = __shfl_down(sufB, d);
        if (lane + d < 64) { sufA += oA; sufB += oB; }
    }
    if (lane == 0) { waveTotA[wv] = sufA; waveTotB[wv] = sufB; }
    lds_barrier();                                        // s2

    // ---- locate threshold bins, broadcast via LDS
    int cumA = sufA - sumA, cumB = sufB - sumB;
    for (int w2 = wv + 1; w2 < NWAVE; ++w2) { cumA += waveTotA[w2]; cumB += waveTotB[w2]; }
    if (cumA < KK && cumA + hA.y >= KK) { bselA = base + 1; bkkA = KK - cumA; }
    cumA += hA.y;
    if (cumA < KK && cumA + hA.x >= KK) { bselA = base;     bkkA = KK - cumA; }
    if (cumB < KK && cumB + hB.y >= KK) { bselB = base + 1; bkkB = KK - cumB; }
    cumB += hB.y;
    if (cumB < KK && cumB + hB.x >= KK) { bselB = base;     bkkB = KK - cumB; }
    lds_barrier();                                        // s3

    const int selA = bselA, kkA = bkkA;
    const int selB = bselB, kkB = bkkB;

    // ---- collect threshold-bin candidates (~30/bin expected)
#pragma unroll
    for (int e = 0; e < EPT; ++e) {
        if (bin_of(pA[e]) == selA) {
            const int pos = atomicAdd(&cntA, 1);
            if (pos < CAND) { ckA[pos] = pA[e]; ciA[pos] = GIDX(e); }
        }
        if (bin_of(pB[e]) == selB) {
            const int pos = atomicAdd(&cntB, 1);
            if (pos < CAND) { ckB[pos] = pB[e]; ciB[pos] = GIDX(e); }
        }
    }
    lds_barrier();                                        // s4

    // ---- membership: 2-bit count per element (A contributes +1, B +1)
    const int cA = cntA < CAND ? cntA : CAND;
    const int cB = cntB < CAND ? cntB : CAND;
    unsigned cnt8 = 0;
#pragma unroll
    for (int e = 0; e < EPT; ++e) {
        const int bA = bin_of(pA[e]);
        if (bA > selA) {
            cnt8 += 1u << (2 * e);
        } else if (bA == selA) {
            const float kl = pA[e]; const int il = GIDX(e);
            int r = 0;
            for (int j = 0; j < cA; ++j)
                r += (ckA[j] > kl || (ckA[j] == kl && ciA[j] < il)) ? 1 : 0;
            if (r < kkA) cnt8 += 1u << (2 * e);
        }
        const int bBv = bin_of(pB[e]);
        if (bBv > selB) {
            cnt8 += 1u << (2 * e);
        } else if (bBv == selB) {
            const float kl = pB[e]; const int il = GIDX(e);
            int r = 0;
            for (int j = 0; j < cB; ++j)
                r += (ckB[j] > kl || (ckB[j] == kl && ciB[j] < il)) ? 1 : 0;
            if (r < kkB) cnt8 += 1u << (2 * e);
        }
    }

    if (MODE == 0) {
        ws[(size_t)blockIdx.x * NT + tid] = (unsigned short)cnt8;
    } else {
        float* orow = out + (size_t)b * NN;
#pragma unroll
        for (int e = 0; e < EPT; ++e) {
            const unsigned c = (cnt8 >> (2 * e)) & 3u;
            if (c) atomicAdd(orow + GIDX(e), (float)c * 0.01f);
        }
    }
}

// Sum 50 packed-2-bit partials per u16 position; each field <= 2, sum <= 100.
// Thread (b,pos): out[b][ (e>>2)*4096 + pos*4 + (e&3) ] for e=0..7.
__global__ __launch_bounds__(256) void reduce_kernel(
    const unsigned short* __restrict__ ws, float* __restrict__ out) {
    const int g   = blockIdx.x * 256 + threadIdx.x;   // 0..131071
    const int b   = g >> 10;
    const int pos = g & 1023;
    int acc[8] = {0, 0, 0, 0, 0, 0, 0, 0};
    for (int ch = 0; ch < SPLIT; ++ch) {
        const unsigned w = ws[((size_t)(b * SPLIT + ch) << 10) + pos];
#pragma unroll
        for (int e = 0; e < 8; ++e) acc[e] += (w >> (2 * e)) & 3u;
    }
    float* ob = out + (size_t)b * NN;
    const float4 o0 = make_float4(acc[0] * 0.01f, acc[1] * 0.01f,
                                  acc[2] * 0.01f, acc[3] * 0.01f);
    const float4 o1 = make_float4(acc[4] * 0.01f, acc[5] * 0.01f,
                                  acc[6] * 0.01f, acc[7] * 0.01f);
    *reinterpret_cast<float4*>(&ob[pos * 4])        = o0;
    *reinterpret_cast<float4*>(&ob[4096 + pos * 4]) = o1;
}

extern "C" void kernel_launch(void* const* d_in, const int* in_sizes, int n_in,
                              void* d_out, int out_size, void* d_ws, size_t ws_size,
                              hipStream_t stream) {
    const float* logits  = (const float*)d_in[0];   // [128, 8192] f32
    const float* uniform = (const float*)d_in[1];   // [128, 100, 8192] f32
    float* out = (float*)d_out;                     // [128, 8192] f32

    const int grid = BB * SPLIT;                    // 6400 blocks
    const size_t need = (size_t)grid * NT * sizeof(unsigned short);  // 13.1 MB

    if (ws_size >= need) {
        gumbel_topk_kernel<0><<<grid, NT, 0, stream>>>(
            logits, uniform, (unsigned short*)d_ws, nullptr);
        reduce_kernel<<<(BB * NN / 8) / 256, 256, 0, stream>>>(
            (const unsigned short*)d_ws, out);
    } else {
        hipMemsetAsync(out, 0, (size_t)out_size * sizeof(float), stream);
        gumbel_topk_kernel<1><<<grid, NT, 0, stream>>>(
            logits, uniform, nullptr, out);
    }
}